// Round 6
// baseline (158.649 us; speedup 1.0000x reference)
//
#include <hip/hip_runtime.h>

// Problem constants
#define N_ROWS 131072    // 32*4096
#define D 64
#define K_CODES 1024

typedef _Float16 f16x8  __attribute__((ext_vector_type(8)));
typedef float    f32x16 __attribute__((ext_vector_type(16)));

#define MFMA32(a, b, c) __builtin_amdgcn_mfma_f32_32x32x16_f16((a), (b), (c), 0, 0, 0)

// ---------------------------------------------------------------------------
// ws layout: csqr[1024] f32 (4 KB) | CBf: 16384 f16x8 units (256 KB)
// NEW 32x32x16 fragment order. Unit index U = tile*512 + f*64 + lane:
//   tile in [0,32) covers codes [tile*32, +32);
//   f in [0,8): f&3 = k-chunk (k0 = (f&3)*16), f>>2 = 0:hi / 1:lo;
//   unit holds the 8 halves lane needs for that MFMA B fragment:
//   B[k=(f&3)*16 + (lane>>5)*8 + j][n=lane&31], code = tile*32 + n.
// CBf stores the hi/lo split of (-2*c); dist = |c|^2 + x.(-2c).
// ---------------------------------------------------------------------------
__global__ __launch_bounds__(256)
void prep_kernel(const float* __restrict__ CB, _Float16* __restrict__ CBf,
                 float* __restrict__ csqr, float* __restrict__ loss) {
    const int b = blockIdx.x, t = threadIdx.x;
    if (b < 64) {
        const int unit = b * 256 + t;          // 0..16383
        const int tile = unit >> 9;            // 0..31
        const int rem  = unit & 511;
        const int f    = rem >> 6;             // 0..7
        const int lane = rem & 63;
        const int code = tile * 32 + (lane & 31);
        const int k0   = (f & 3) * 16 + (lane >> 5) * 8;
        const float* src = CB + (size_t)code * D + k0;
        float4 v0 = *(const float4*)(src);
        float4 v1 = *(const float4*)(src + 4);
        float xs[8] = {v0.x, v0.y, v0.z, v0.w, v1.x, v1.y, v1.z, v1.w};
        f16x8 o;
#pragma unroll
        for (int j = 0; j < 8; ++j) {
            float sv = -2.0f * xs[j];
            _Float16 h = (_Float16)sv;
            o[j] = (f < 4) ? h : (_Float16)(sv - (float)h);
        }
        *(f16x8*)(CBf + (size_t)unit * 8) = o;
    } else {
        if (t == 0) *loss = 0.0f;
        for (int k = t; k < K_CODES; k += 256) {
            const float4* p = (const float4*)(CB + (size_t)k * D);
            float s = 0.0f;
#pragma unroll
            for (int i = 0; i < 16; ++i) {
                float4 v = p[i];
                s += v.x * v.x + v.y * v.y + v.z * v.z + v.w * v.w;
            }
            csqr[k] = s;
        }
    }
}

// ---------------------------------------------------------------------------
// Direct global->LDS 16B copy (lane-linear dest: wave-uniform base + lane*16).
// ---------------------------------------------------------------------------
__device__ __forceinline__ void gload_lds16(const void* g, void* l) {
    __builtin_amdgcn_global_load_lds(
        (const __attribute__((address_space(1))) void*)g,
        (__attribute__((address_space(3))) void*)l,
        16, 0, 0);
}

// ---------------------------------------------------------------------------
// K1 (32x32x16 MFMA core): block = 4 waves x 32 rows = 128 rows, each wave
// covers ALL 1024 codes as 32 tiles of 32 codes. CHANGE vs rounds 3-5
// (63.7-66us plateau, MfmaUtil ~33%, insensitive to schedule/ILP/barriers):
// coarser MFMA grain — 12x fewer, 4x-larger MFMA instructions per tile
// (12x mfma_f32_32x32x16_f16 per 32r x 32c vs 48x 16x16x32), ceiling
// 2075->2382 TF. One 32x32 acc per tile (16 f32/lane). Macro-schedule is
// round-5's verified 1-barrier ring: 2-buf x 2-tile (8KB/tile) LDS ring,
// 16 groups, vmcnt(0)+s_barrier per group, STAGE(g+1) right after.
// Layouts: A[m=lane&31][k=(lane>>5)*8+j] (rows Rw+m); B per CBf above;
// C/D col=lane&31, row=(reg&3)+8*(reg>>2)+4*(lane>>5) [m74/m101-verified].
// Split algebra unchanged: hh + lh + hl (ll ~2^-24 dropped), acc-init=csqr.
// Tie-break = global first-min: tiles ascend in-lane (strict <), 32-lane
// column reduce (xor 1..16, stays within lane-half) is index-lexicographic.
// LDS 36.7 KB -> 4 blocks/CU; grid 1024 = 4/CU.
// ---------------------------------------------------------------------------
__global__ __launch_bounds__(256, 4)
void argmin_kernel(const float* __restrict__ X,
                   const _Float16* __restrict__ CBf,
                   const float* __restrict__ csqr,
                   const float* __restrict__ CB,
                   float* __restrict__ out) {
    __shared__ _Float16 Bring[2][2][4096];   // 2 bufs x 2 tiles x 8 KB
    __shared__ float LsC[K_CODES];           // csqr copy, 4 KB
    __shared__ int   ivfin[128];
    __shared__ float lsum[4];

    const int t    = threadIdx.x;
    const int wave = t >> 6;
    const int lane = t & 63;
    const int col  = lane & 31;              // code column within tile
    const int hi5  = lane >> 5;              // k-half / row-offset selector
    const int R0   = blockIdx.x * 128;
    const int Rw   = R0 + wave * 32;

// Stage group g (2 tiles = 1024 units of 16B) into buf: thread t loads
// units i*256+t, dest LDS byte offset = unit_local*16 (lane-linear).
#define STAGE(g_, buf_)                                                       \
    do {                                                                      \
        _Pragma("unroll")                                                     \
        for (int i_ = 0; i_ < 4; ++i_) {                                      \
            const int u_ = i_ * 256 + t;                                      \
            const f16x8* gp_ =                                                \
                (const f16x8*)CBf + (size_t)((g_) * 1024 + u_);               \
            gload_lds16((const void*)gp_,                                     \
                        (void*)((char*)&Bring[buf_][0][0] + (size_t)u_ * 16));\
        }                                                                     \
    } while (0)

    STAGE(0, 0);                       // group 0 in flight ASAP

    // csqr -> LDS (covered by the prologue __syncthreads).
    ((float4*)LsC)[t] = ((const float4*)csqr)[t];

    // ---- A fragments: split(x) hi/lo. Lane holds row m = Rw + col,
    // k = c*16 + hi5*8 + j (c = 0..3). Lanes l and l+32 share a row and
    // partition its 64 columns -> full-wave xsq counts each element once.
    f16x8 Ah[4], Al[4];
    float xsq = 0.0f;
    {
        const float* xr = X + (size_t)(Rw + col) * D;
#pragma unroll
        for (int c = 0; c < 4; ++c) {
            const int k0 = c * 16 + hi5 * 8;
            float4 v0 = *(const float4*)(xr + k0);
            float4 v1 = *(const float4*)(xr + k0 + 4);
            float xs[8] = {v0.x, v0.y, v0.z, v0.w, v1.x, v1.y, v1.z, v1.w};
            f16x8 h, l;
#pragma unroll
            for (int j = 0; j < 8; ++j) {
                xsq += xs[j] * xs[j];
                _Float16 hh = (_Float16)xs[j];
                h[j] = hh;
                l[j] = (_Float16)(xs[j] - (float)hh);
            }
            Ah[c] = h;
            Al[c] = l;
        }
    }

    float bestd[16];
    int   besti[16];
#pragma unroll
    for (int s = 0; s < 16; ++s) { bestd[s] = 3.0e38f; besti[s] = 0; }

// Consume tile i_ (0/1) of group g: 8 ds_read_b128 + 12 MFMA + argmin.
#define TILECOMP(i_)                                                          \
    do {                                                                      \
        const f16x8* Bt_ = (const f16x8*)&Bring[g & 1][i_][0];                \
        const int   T_  = g * 2 + (i_);                                       \
        const int   ci_ = T_ * 32 + col;                                      \
        const float cs_ = LsC[ci_];                                           \
        f16x8 bh[4], bl[4];                                                   \
        _Pragma("unroll")                                                     \
        for (int c = 0; c < 4; ++c) bh[c] = Bt_[c * 64 + lane];               \
        _Pragma("unroll")                                                     \
        for (int c = 0; c < 4; ++c) bl[c] = Bt_[(4 + c) * 64 + lane];         \
        f32x16 acc;                                                           \
        _Pragma("unroll")                                                     \
        for (int s = 0; s < 16; ++s) acc[s] = cs_;                            \
        _Pragma("unroll")                                                     \
        for (int c = 0; c < 4; ++c) acc = MFMA32(Ah[c], bh[c], acc);          \
        _Pragma("unroll")                                                     \
        for (int c = 0; c < 4; ++c) acc = MFMA32(Al[c], bh[c], acc);          \
        _Pragma("unroll")                                                     \
        for (int c = 0; c < 4; ++c) acc = MFMA32(Ah[c], bl[c], acc);          \
        _Pragma("unroll")                                                     \
        for (int s = 0; s < 16; ++s) {                                        \
            bool lt = acc[s] < bestd[s];                                      \
            bestd[s] = lt ? acc[s] : bestd[s];                                \
            besti[s] = lt ? ci_ : besti[s];                                   \
        }                                                                     \
    } while (0)

    __syncthreads();   // LsC + group 0 fully resident (full drain, prologue only)

    // ---- Group 0: stage group 1, consume group 0.
    {
        const int g = 0;
        STAGE(1, 1);
        TILECOMP(0);
        TILECOMP(1);
    }
    // ---- Groups 1..15: ONE vmcnt(0)+barrier per group (round-5 schedule).
    for (int g = 1; g < 16; ++g) {
        asm volatile("s_waitcnt vmcnt(0)" ::: "memory");
        __builtin_amdgcn_s_barrier();
        if (g < 15) STAGE(g + 1, (g + 1) & 1);
        TILECOMP(0);
        TILECOMP(1);
    }

    // ---- Finalize: reduce each of the 16 row-slots across the 32 code
    // columns (xor masks 1..16 keep lane-half intact; lexicographic on
    // exact ties). col==0 lanes (0 and 32) hold rows
    // r = (s&3) + 8*(s>>2) + 4*hi5.
    float dvsum = 0.0f;
#pragma unroll
    for (int s = 0; s < 16; ++s) {
        float dv = bestd[s];
        int   iv = besti[s];
#pragma unroll
        for (int m = 1; m < 32; m <<= 1) {
            float od = __shfl_xor(dv, m, 64);
            int   oi = __shfl_xor(iv, m, 64);
            if (od < dv || (od == dv && oi < iv)) { dv = od; iv = oi; }
        }
        if (col == 0) {
            const int r  = (s & 3) + 8 * (s >> 2) + 4 * hi5;   // 0..31
            const int rl = wave * 32 + r;                      // 0..127
            ivfin[rl] = iv;
            out[1 + (size_t)N_ROWS * D + R0 + rl] = (float)iv; // idxf
            dvsum += dv;
        }
    }

    // ---- Loss partial: xsq (all lanes) + dvsum (col==0 lanes) reduce.
    {
        float s = xsq + dvsum;
#pragma unroll
        for (int m = 1; m < 64; m <<= 1) s += __shfl_xor(s, m, 64);
        if (lane == 0) lsum[wave] = s;
    }
    __syncthreads();                             // ivfin + lsum ready

    const float scale = 1.25f / (float)((size_t)N_ROWS * D);
    if (t == 0)
        atomicAdd(out, (lsum[0] + lsum[1] + lsum[2] + lsum[3]) * scale);

    // ---- Block-cooperative zq span write: dwords [R0*64, R0*64+8192) at
    // out+1. Global dword offset 1+R0*64+j is 16B-aligned iff j%4==3.
    float* p = out + 1 + (size_t)R0 * D;
#pragma unroll
    for (int i = 0; i < 8; ++i) {
        int q = i * 256 + t;        // 0..2047
        int j = 4 * q + 3;          // 3,7,...,8191
        if (q < 2047) {
            float v[4];
#pragma unroll
            for (int e = 0; e < 4; ++e) {
                int jj = j + e;     // may straddle a row boundary
                v[e] = CB[(size_t)ivfin[jj >> 6] * D + (jj & 63)];
            }
            *(float4*)(p + j) = make_float4(v[0], v[1], v[2], v[3]);
        } else if (q == 2047) {
            p[8191] = CB[(size_t)ivfin[127] * D + 63];
        }
    }
    if (t == 0) {   // head dwords j=0..2 (row 0, cols 0..2)
        const float* c0 = CB + (size_t)ivfin[0] * D;
        p[0] = c0[0];
        p[1] = c0[1];
        p[2] = c0[2];
    }
}

// ---------------------------------------------------------------------------
extern "C" void kernel_launch(void* const* d_in, const int* in_sizes, int n_in,
                              void* d_out, int out_size, void* d_ws,
                              size_t ws_size, hipStream_t stream) {
    const float* X  = (const float*)d_in[0];   // inputs  [131072,64]
    const float* CB = (const float*)d_in[1];   // codebook [1024,64]

    float*    csqr = (float*)d_ws;                      // 4 KB
    _Float16* CBf  = (_Float16*)((char*)d_ws + 4096);   // 256 KB

    hipLaunchKernelGGL(prep_kernel, dim3(65), dim3(256), 0, stream,
                       CB, CBf, csqr, (float*)d_out);
    hipLaunchKernelGGL(argmin_kernel, dim3(N_ROWS / 128), dim3(256), 0, stream,
                       X, CBf, csqr, CB, (float*)d_out);
}

// Round 7
// 149.238 us; speedup vs baseline: 1.0631x; 1.0631x over previous
//
#include <hip/hip_runtime.h>

// Problem constants
#define N_ROWS 131072    // 32*4096
#define D 64
#define K_CODES 1024

typedef _Float16 f16x8 __attribute__((ext_vector_type(8)));
typedef float    f32x4 __attribute__((ext_vector_type(4)));

#define MFMA16(a, b, c) __builtin_amdgcn_mfma_f32_16x16x32_f16((a), (b), (c), 0, 0, 0)

// ---------------------------------------------------------------------------
// ws layout: csqr[1024] f32 (4 KB) | CBf: 16384 f16x8 units (256 KB)
// 16x16x32 fragment order (REVERTED from round-6's 32x32 layout).
// CBf unit index = tile*256 + f*64 + lane, f in {0:hi k0-31, 1:hi k32-63,
// 2:lo k0-31, 3:lo k32-63}; unit holds the 8 halves lane needs for that
// MFMA B fragment: B[k=(lane>>4)*8+j][n=lane&15], code = tile*16 + n.
// CBf stores the hi/lo split of (-2*c); dist = |c|^2 + x.(-2c).
// (Correctness-verified rounds 2-5.)
// ---------------------------------------------------------------------------
__global__ __launch_bounds__(256)
void prep_kernel(const float* __restrict__ CB, _Float16* __restrict__ CBf,
                 float* __restrict__ csqr, float* __restrict__ loss) {
    const int b = blockIdx.x, t = threadIdx.x;
    if (b < 64) {
        const int unit = b * 256 + t;
        const int tile = unit >> 8;
        const int f    = (unit >> 6) & 3;
        const int lane = unit & 63;
        const int quad = lane >> 4, lrow = lane & 15;
        const int code = tile * 16 + lrow;
        const int k0   = (f & 1) * 32 + quad * 8;
        const float* src = CB + (size_t)code * D + k0;
        float4 v0 = *(const float4*)(src);
        float4 v1 = *(const float4*)(src + 4);
        float xs[8] = {v0.x, v0.y, v0.z, v0.w, v1.x, v1.y, v1.z, v1.w};
        f16x8 o;
#pragma unroll
        for (int j = 0; j < 8; ++j) {
            float sv = -2.0f * xs[j];
            _Float16 h = (_Float16)sv;
            o[j] = (f < 2) ? h : (_Float16)(sv - (float)h);
        }
        *(f16x8*)(CBf + (size_t)unit * 8) = o;
    } else {
        if (t == 0) *loss = 0.0f;
        for (int k = t; k < K_CODES; k += 256) {
            const float4* p = (const float4*)(CB + (size_t)k * D);
            float s = 0.0f;
#pragma unroll
            for (int i = 0; i < 16; ++i) {
                float4 v = p[i];
                s += v.x * v.x + v.y * v.y + v.z * v.z + v.w * v.w;
            }
            csqr[k] = s;
        }
    }
}

// ---------------------------------------------------------------------------
// Direct global->LDS 16B copy (lane-linear dest: wave-uniform base + lane*16).
// ---------------------------------------------------------------------------
__device__ __forceinline__ void gload_lds16(const void* g, void* l) {
    __builtin_amdgcn_global_load_lds(
        (const __attribute__((address_space(1))) void*)g,
        (__attribute__((address_space(3))) void*)l,
        16, 0, 0);
}

// ---------------------------------------------------------------------------
// K1 (8 waves/SIMD occupancy): block = 8 waves x 16 rows = 128 rows (MT=1),
// each wave covers ALL 1024 codes. CHANGE vs rounds 3-5 (63.7-66us plateau,
// MfmaUtil ~33%, insensitive to ILP/barriers/vmcnt — all within-wave fixes):
// the untested resource is RESIDENT WAVES. 512-thread blocks + MT=1 halve
// per-wave state (~55 VGPR <= the 64-reg bound for 8 waves/SIMD) at the
// same LDS (36.7 KB -> 4 blocks/CU) and same grid 1024 -> 32 waves/CU =
// 8/SIMD, double round 3's 4/SIMD, covering whole-wave stall time (barrier
// skew + LDS/L2 service) that per-wave scheduling could not.
// Schedule = round 3's verified 2-barrier ring: 2-buf x 4-tile LDS ring,
// STAGE(g+1) (2 gload_lds/thread) -> vmcnt(2) -> barrier -> consume ->
// barrier. Per tile per wave: 4 ds_read_b128 + 6 MFMA (hh,hh,lh,lh,hl,hl;
// ll ~2^-24 dropped) + 4-slot argmin. Tie-break = global first-min: tiles
// ascend in-lane (strict <), 16-lane column reduce index-lexicographic.
// No cross-wave merge (waves own disjoint rows).
// ---------------------------------------------------------------------------
__global__ __launch_bounds__(512, 8)
void argmin_kernel(const float* __restrict__ X,
                   const _Float16* __restrict__ CBf,
                   const float* __restrict__ csqr,
                   const float* __restrict__ CB,
                   float* __restrict__ out) {
    __shared__ _Float16 Bring[2][4][2048];   // 2 bufs x 4 tiles x 4 KB
    __shared__ float LsC[K_CODES];           // csqr copy, 4 KB
    __shared__ int   ivfin[128];
    __shared__ float lsum[8];

    const int t    = threadIdx.x;            // 0..511
    const int wave = t >> 6;                 // 0..7
    const int lane = t & 63;
    const int quad = lane >> 4;
    const int lrow = lane & 15;
    const int R0   = blockIdx.x * 128;
    const int Rw   = R0 + wave * 16;         // this wave's 16 rows

// Stage group g (4 tiles = 1024 units of 16B) into buf: 512 threads x 2
// loads. u_local = i_*512 + t = wave-uniform base + lane (lane-linear).
#define STAGE(g_, buf_)                                                       \
    do {                                                                      \
        _Pragma("unroll")                                                     \
        for (int i_ = 0; i_ < 2; ++i_) {                                      \
            const int u_ = i_ * 512 + t;                                      \
            const f16x8* gp_ =                                                \
                (const f16x8*)CBf + (size_t)((g_) * 1024 + u_);               \
            gload_lds16((const void*)gp_,                                     \
                        (void*)((char*)&Bring[buf_][0][0] + (size_t)u_ * 16));\
        }                                                                     \
    } while (0)

    STAGE(0, 0);                       // group 0 in flight ASAP

    // csqr -> LDS (covered by the prologue __syncthreads).
    if (t < 256) ((float4*)LsC)[t] = ((const float4*)csqr)[t];

    // ---- A fragments (MT=1): split(x) hi/lo. Lane holds
    // A[m=lrow][k=quad*8+j] for row Rw+lrow; ks*32 covers k-halves.
    // Full wave covers its 16 rows x 64 cols exactly once -> xsq.
    f16x8 Ah[2], Al[2];
    float xsq = 0.0f;
    {
        const float* xr = X + (size_t)(Rw + lrow) * D;
#pragma unroll
        for (int ks = 0; ks < 2; ++ks) {
            const int k0 = ks * 32 + quad * 8;
            float4 v0 = *(const float4*)(xr + k0);
            float4 v1 = *(const float4*)(xr + k0 + 4);
            float xs[8] = {v0.x, v0.y, v0.z, v0.w, v1.x, v1.y, v1.z, v1.w};
            f16x8 h, l;
#pragma unroll
            for (int j = 0; j < 8; ++j) {
                xsq += xs[j] * xs[j];
                _Float16 hh = (_Float16)xs[j];
                h[j] = hh;
                l[j] = (_Float16)(xs[j] - (float)hh);
            }
            Ah[ks] = h;
            Al[ks] = l;
        }
    }

    float bestd[4];
    int   besti[4];
#pragma unroll
    for (int r = 0; r < 4; ++r) { bestd[r] = 3.0e38f; besti[r] = 0; }

    __syncthreads();   // LsC + group 0 ready (full drain — prologue only)

    // ---- Main loop: 16 groups x 4 tiles, round-3 2-barrier schedule.
    // STAGE issues 2 loads; before consuming group g exactly the 2 loads of
    // group g+1 may remain outstanding -> vmcnt(2) retires g's loads.
    for (int g = 0; g < 16; ++g) {
        if (g < 15) {
            STAGE(g + 1, (g + 1) & 1);
            asm volatile("s_waitcnt vmcnt(2)" ::: "memory");
        } else {
            asm volatile("s_waitcnt vmcnt(0)" ::: "memory");
        }
        __builtin_amdgcn_s_barrier();            // group g fully in LDS
        __builtin_amdgcn_sched_barrier(0);
        const _Float16* Bb = &Bring[g & 1][0][0];
#pragma unroll
        for (int i = 0; i < 4; ++i) {
            const f16x8* Bt = (const f16x8*)(Bb + i * 2048) + lane;
            f16x8 b0 = Bt[0], b1 = Bt[64], b2 = Bt[128], b3 = Bt[192];
            const int   c  = (g * 4 + i) * 16 + lrow;
            const float cs = LsC[c];
            f32x4 acc = {cs, cs, cs, cs};
            acc = MFMA16(Ah[0], b0, acc);
            acc = MFMA16(Ah[1], b1, acc);
            acc = MFMA16(Al[0], b0, acc);
            acc = MFMA16(Al[1], b1, acc);
            acc = MFMA16(Ah[0], b2, acc);
            acc = MFMA16(Ah[1], b3, acc);
#pragma unroll
            for (int r = 0; r < 4; ++r) {
                bool lt = acc[r] < bestd[r];
                bestd[r] = lt ? acc[r] : bestd[r];
                besti[r] = lt ? c : besti[r];
            }
        }
        __builtin_amdgcn_sched_barrier(0);       // pin reads/MFMAs here
        __builtin_amdgcn_s_barrier();            // all waves done with buf
    }

    // ---- Finalize: 16-lane column reduce (lexicographic on exact ties);
    // lrow==0 lanes hold rows Rw + quad*4 + r (C layout: row = quad*4 + r,
    // col = lrow — verified rounds 0-5).
    float dvsum = 0.0f;
#pragma unroll
    for (int r = 0; r < 4; ++r) {
        float dv = bestd[r];
        int   iv = besti[r];
#pragma unroll
        for (int m = 1; m < 16; m <<= 1) {
            float od = __shfl_xor(dv, m, 64);
            int   oi = __shfl_xor(iv, m, 64);
            if (od < dv || (od == dv && oi < iv)) { dv = od; iv = oi; }
        }
        if (lrow == 0) {
            const int rl = wave * 16 + quad * 4 + r;            // 0..127
            ivfin[rl] = iv;
            out[1 + (size_t)N_ROWS * D + R0 + rl] = (float)iv;  // idxf
            dvsum += dv;
        }
    }

    // ---- Loss partial: xsq (all lanes) + dvsum (lrow==0 lanes) reduce.
    {
        float s = xsq + dvsum;
#pragma unroll
        for (int m = 1; m < 64; m <<= 1) s += __shfl_xor(s, m, 64);
        if (lane == 0) lsum[wave] = s;
    }
    __syncthreads();                             // ivfin + lsum ready

    const float scale = 1.25f / (float)((size_t)N_ROWS * D);
    if (t == 0) {
        float L = 0.0f;
#pragma unroll
        for (int w = 0; w < 8; ++w) L += lsum[w];
        atomicAdd(out, L * scale);
    }

    // ---- Block-cooperative zq span write: dwords [R0*64, R0*64+8192) at
    // out+1. Global dword offset 1+R0*64+j is 16B-aligned iff j%4==3.
    float* p = out + 1 + (size_t)R0 * D;
#pragma unroll
    for (int i = 0; i < 4; ++i) {
        int q = i * 512 + t;        // 0..2047
        int j = 4 * q + 3;          // 3,7,...,8191
        if (q < 2047) {
            float v[4];
#pragma unroll
            for (int e = 0; e < 4; ++e) {
                int jj = j + e;     // may straddle a row boundary
                v[e] = CB[(size_t)ivfin[jj >> 6] * D + (jj & 63)];
            }
            *(float4*)(p + j) = make_float4(v[0], v[1], v[2], v[3]);
        } else if (q == 2047) {
            p[8191] = CB[(size_t)ivfin[127] * D + 63];
        }
    }
    if (t == 0) {   // head dwords j=0..2 (row 0, cols 0..2)
        const float* c0 = CB + (size_t)ivfin[0] * D;
        p[0] = c0[0];
        p[1] = c0[1];
        p[2] = c0[2];
    }
}

// ---------------------------------------------------------------------------
extern "C" void kernel_launch(void* const* d_in, const int* in_sizes, int n_in,
                              void* d_out, int out_size, void* d_ws,
                              size_t ws_size, hipStream_t stream) {
    const float* X  = (const float*)d_in[0];   // inputs  [131072,64]
    const float* CB = (const float*)d_in[1];   // codebook [1024,64]

    float*    csqr = (float*)d_ws;                      // 4 KB
    _Float16* CBf  = (_Float16*)((char*)d_ws + 4096);   // 256 KB

    hipLaunchKernelGGL(prep_kernel, dim3(65), dim3(256), 0, stream,
                       CB, CBf, csqr, (float*)d_out);
    hipLaunchKernelGGL(argmin_kernel, dim3(N_ROWS / 128), dim3(512), 0, stream,
                       X, CBf, csqr, CB, (float*)d_out);
}